// Round 9
// baseline (155.059 us; speedup 1.0000x reference)
//
#include <hip/hip_runtime.h>
#include <hip/hip_bf16.h>
#include <stdint.h>

typedef unsigned short u16;
typedef unsigned int u32;
typedef __bf16 bf16x8 __attribute__((ext_vector_type(8)));
typedef _Float16 f16x8 __attribute__((ext_vector_type(8)));
typedef float f32x4 __attribute__((ext_vector_type(4)));

__device__ __forceinline__ u16 f2h(float f) {
  return __builtin_bit_cast(u16, (_Float16)f);
}

__device__ __forceinline__ void gload_lds16(const void* g, void* l) {
  __builtin_amdgcn_global_load_lds(
      (const __attribute__((address_space(1))) u32*)g,
      (__attribute__((address_space(3))) u32*)l, 16, 0, 0);
}

// ---------------- concat + f32->f16 ----------------
__global__ void k_concat_f16(const float* __restrict__ x, const float* __restrict__ y,
                             u16* __restrict__ xyh) {
  int tid = blockIdx.x * blockDim.x + threadIdx.x;
  int e = tid * 4;
  int s = e >> 9;
  int d = e & 511;
  int b = s >> 11, r = s & 2047;
  const float* src = (r < 1024) ? (x + ((size_t)(b * 1024 + r) * 512 + d))
                                : (y + ((size_t)(b * 1024 + (r - 1024)) * 512 + d));
  float4 v = *(const float4*)src;
  ushort4 o;
  o.x = f2h(v.x); o.y = f2h(v.y); o.z = f2h(v.z); o.w = f2h(v.w);
  *(ushort4*)(xyh + e) = o;
}

// ---------------- W~ = Wq^T * Wk, e-split partials ----------------
// grid 256 = 64 (i,j)-tiles x 4 e-groups(128 e); wpart[eg][j][i] f32 (transposed: W~T)
__global__ __launch_bounds__(256) void k_wtilde_part(const float* __restrict__ Wq,
                                                     const float* __restrict__ Wk,
                                                     float* __restrict__ wpart) {
  int blk = blockIdx.x;
  int eg = blk >> 6, tile = blk & 63;
  int i0 = (tile >> 3) * 64, j0 = (tile & 7) * 64;
  int t = threadIdx.x;
  __shared__ float qs[64][64], ks[64][64];
  int ti = t >> 4, tj = t & 15;  // 16x16 threads, 4x4 outputs each
  float acc[4][4] = {};
  for (int ec = eg * 128; ec < eg * 128 + 128; ec += 64) {
    __syncthreads();
#pragma unroll
    for (int r = 0; r < 4; ++r) {
      int e = (t >> 4) + r * 16;
      int c = (t & 15) * 4;
      *(float4*)&qs[e][c] = *(const float4*)(Wq + (size_t)(ec + e) * 512 + i0 + c);
      *(float4*)&ks[e][c] = *(const float4*)(Wk + (size_t)(ec + e) * 512 + j0 + c);
    }
    __syncthreads();
#pragma unroll 8
    for (int e = 0; e < 64; ++e) {
      float4 qa = *(const float4*)&qs[e][ti * 4];
      float4 kb = *(const float4*)&ks[e][tj * 4];
      float qv[4] = {qa.x, qa.y, qa.z, qa.w}, kv[4] = {kb.x, kb.y, kb.z, kb.w};
#pragma unroll
      for (int a = 0; a < 4; ++a)
#pragma unroll
        for (int b = 0; b < 4; ++b) acc[a][b] += qv[a] * kv[b];
    }
  }
  float* base = wpart + (size_t)eg * 262144;
#pragma unroll
  for (int b = 0; b < 4; ++b) {
    float4 o = {acc[0][b], acc[1][b], acc[2][b], acc[3][b]};
    *(float4*)(base + (size_t)(j0 + tj * 4 + b) * 512 + i0 + ti * 4) = o;
  }
}

// ---------------- finalize W~T (sum 4 partials -> f16) + Wv -> f16 ----------------
__global__ __launch_bounds__(256) void k_wfin(const float* __restrict__ wpart,
                                              const float* __restrict__ Wv,
                                              u16* __restrict__ WtT, u16* __restrict__ Wvh) {
  int blk = blockIdx.x, t = threadIdx.x;
  if (blk < 64) {
    int base = blk * 4096 + t * 16;
#pragma unroll
    for (int g = 0; g < 4; ++g) {
      float4 s = *(const float4*)(wpart + base + g * 4);
#pragma unroll
      for (int eg = 1; eg < 4; ++eg) {
        float4 p = *(const float4*)(wpart + (size_t)eg * 262144 + base + g * 4);
        s.x += p.x; s.y += p.y; s.z += p.z; s.w += p.w;
      }
      ushort4 o;
      o.x = f2h(s.x); o.y = f2h(s.y); o.z = f2h(s.z); o.w = f2h(s.w);
      *(ushort4*)(WtT + base + g * 4) = o;
    }
  } else {
    int base = (blk - 64) * 65536;
#pragma unroll 16
    for (int r = 0; r < 64; ++r) {
      int e = base + (r * 256 + t) * 4;
      float4 v = *(const float4*)(Wv + e);
      ushort4 o;
      o.x = f2h(v.x); o.y = f2h(v.y); o.z = f2h(v.z); o.w = f2h(v.w);
      *(ushort4*)(Wvh + e) = o;
    }
  }
}

// ---------------- 256-tile GEMM (round-4 schedule): C = scale * A * B^T ----------------
// BM=256, BK=64, 8 waves. BN=256: waves 2x4 (wave tile 128x64). BN=128: 4x2 (64x64).
// All operands f16. LDS rows 128B XOR-swizzled (pre-swizzled global_load_lds source),
// double-buffered; stage ALL of tile kt+1 at top of tile kt; one vmcnt(0)+barrier/tile.
// EXPSUM: C = exp2(acc*scale) f16 (scale pre-folded with 1/sqrt(D)*log2e) +
//         per-row partial sums -> lextra[(z*2048+row)*ntiles+ty].
// DIVL:   C = acc*scale*lextra[z*2048+row] (f32 out), lextra = 1/l.
template <int BN, int OUTM, int EXPSUM, int DIVL>
__global__ __launch_bounds__(512, 2) void k_gemm256(
    const u16* __restrict__ A, const u16* __restrict__ B, void* __restrict__ Cv,
    int lda, int ldb, int ldc,
    long long sA, long long sB, long long sC,
    int K, float scale, int batches, int mtiles, int ntiles,
    float* __restrict__ lextra) {
  constexpr int M_rep = (BN == 256) ? 8 : 4;
  constexpr int WN = (BN == 256) ? 4 : 2;
  constexpr int NPH = (BN == 256) ? 4 : 2;
  constexpr int A_BYTES = 256 * 128;
  constexpr int B_BYTES = BN * 128;
  constexpr int BUFB = A_BYTES + B_BYTES;
  constexpr int RND_A = A_BYTES / 8192;  // 4
  constexpr int RND_B = B_BYTES / 8192;  // 4 / 2
  constexpr int RNDS = RND_A + RND_B;    // 8 / 6

  __shared__ __align__(16) char lds[2 * BUFB];

  int t = threadIdx.x;
  int lane = t & 63;
  int w = t >> 6;
  int wr = w / WN, wc = w % WN;

  int bid = blockIdx.x;
  long long z = bid % batches;
  int t2 = bid / batches;
  int tx = t2 % mtiles, ty = t2 / mtiles;

  size_t rsA = (size_t)lda * 2, rsB = (size_t)ldb * 2;
  int srow = t >> 3;
  int scb = ((t & 7) * 16) ^ ((srow & 7) << 4);  // pre-swizzled source byte col

  const char* Ab = (const char*)(A + z * sA + (size_t)tx * 256 * lda);
  const char* Bb = (const char*)(B + z * sB + (size_t)ty * BN * ldb);

  const char* gsrc[RNDS];
#pragma unroll
  for (int r = 0; r < RNDS; ++r) {
    if (r < RND_A) gsrc[r] = Ab + (size_t)(r * 64 + srow) * rsA + scb;
    else           gsrc[r] = Bb + (size_t)((r - RND_A) * 64 + srow) * rsB + scb;
  }

  auto stageAll = [&](int buf) {
#pragma unroll
    for (int r = 0; r < RNDS; ++r) {
      int off = ((r < RND_A) ? r * 8192 : A_BYTES + (r - RND_A) * 8192) + t * 16;
      gload_lds16(gsrc[r], lds + buf * BUFB + off);
      gsrc[r] += 128;  // advance one K-tile
    }
  };

  int axor = (lane & 7) << 4;
  int arow0 = wr * (M_rep * 16) + (lane & 15);
  int brow0 = wc * 64 + (lane & 15);
  int kb0 = (lane >> 4) * 16;

  f32x4 acc[M_rep][4] = {};
  int NT = K >> 6;

  stageAll(0);
  asm volatile("s_waitcnt vmcnt(0)" ::: "memory");
  __syncthreads();

  for (int kt = 0; kt < NT; ++kt) {
    const char* Abase = lds + (kt & 1) * BUFB;
    const char* Bbase = Abase + A_BYTES;
    if (kt + 1 < NT) stageAll((kt & 1) ^ 1);
    __builtin_amdgcn_sched_barrier(0);

    f16x8 afr[4][2];
#pragma unroll
    for (int p = 0; p < NPH; ++p) {
      int mchunk = (p >> 1) * 4;
      int npair = (p & 1) * 2;
      if ((p & 1) == 0) {
#pragma unroll
        for (int i = 0; i < 4; ++i)
#pragma unroll
          for (int kk = 0; kk < 2; ++kk)
            afr[i][kk] = *(const f16x8*)(Abase + (arow0 + (mchunk + i) * 16) * 128 +
                                         ((kb0 + kk * 64) ^ axor));
      }
      f16x8 bfr[2][2];
#pragma unroll
      for (int j = 0; j < 2; ++j)
#pragma unroll
        for (int kk = 0; kk < 2; ++kk)
          bfr[j][kk] = *(const f16x8*)(Bbase + (brow0 + (npair + j) * 16) * 128 +
                                       ((kb0 + kk * 64) ^ axor));
      __builtin_amdgcn_s_setprio(1);
#pragma unroll
      for (int i = 0; i < 4; ++i)
#pragma unroll
        for (int j = 0; j < 2; ++j)
#pragma unroll
          for (int kk = 0; kk < 2; ++kk)
            acc[mchunk + i][npair + j] = __builtin_amdgcn_mfma_f32_16x16x32_f16(
                afr[i][kk], bfr[j][kk], acc[mchunk + i][npair + j], 0, 0, 0);
      __builtin_amdgcn_s_setprio(0);
    }

    if (kt + 1 < NT) {
      asm volatile("s_waitcnt vmcnt(0)" ::: "memory");
      __syncthreads();
    }
  }

  // ---------------- epilogue ----------------
  float* lds_l = (float*)lds;  // [256][WN] row-sum staging (EXPSUM only)
  if constexpr (EXPSUM) __syncthreads();

#pragma unroll
  for (int m = 0; m < M_rep; ++m) {
    int lrow = wr * (M_rep * 16) + m * 16 + ((lane >> 4) << 2);
    int grow = tx * 256 + lrow;
#pragma unroll
    for (int r = 0; r < 4; ++r) {
      float rs = 0.0f;
      float linv_v = 1.0f;
      if constexpr (DIVL) linv_v = lextra[z * 2048 + grow + r];
#pragma unroll
      for (int n = 0; n < 4; ++n) {
        int col = ty * BN + wc * 64 + n * 16 + (lane & 15);
        size_t idx = (size_t)(z * sC) + (size_t)(grow + r) * ldc + col;
        if constexpr (EXPSUM) {
          _Float16 h = (_Float16)exp2f(acc[m][n][r] * scale);  // scale = 1/sqrt(D)*log2e
          ((_Float16*)Cv)[idx] = h;
          rs += (float)h;  // sum rounded values so O/l is unbiased
        } else if constexpr (OUTM == 1) {
          ((_Float16*)Cv)[idx] = (_Float16)(acc[m][n][r] * scale);
        } else {
          ((float*)Cv)[idx] = acc[m][n][r] * scale * linv_v;
        }
      }
      if constexpr (EXPSUM) {
        rs += __shfl_xor(rs, 1, 16);
        rs += __shfl_xor(rs, 2, 16);
        rs += __shfl_xor(rs, 4, 16);
        rs += __shfl_xor(rs, 8, 16);
        if ((lane & 15) == 0) lds_l[(lrow + r) * WN + wc] = rs;
      }
    }
  }

  if constexpr (EXPSUM) {
    __syncthreads();
    if (t < 256) {
      float s = 0.0f;
#pragma unroll
      for (int q = 0; q < WN; ++q) s += lds_l[t * WN + q];
      lextra[(z * 2048 + tx * 256 + t) * ntiles + ty] = s;
    }
  }
}

// ---------------- invert row sums ----------------
__global__ __launch_bounds__(256) void k_inv_l(const float* __restrict__ lpart,
                                               float* __restrict__ linv,
                                               int mrows, int rowoff, int nparts) {
  int tid = blockIdx.x * blockDim.x + threadIdx.x;
  int z = tid / mrows, lr = tid - z * mrows;
  int row = z * 2048 + rowoff + lr;
  const float* p = lpart + (size_t)row * nparts;
  float s = 0.0f;
  for (int q = 0; q < nparts; ++q) s += p[q];
  linv[row] = 1.0f / s;
}

extern "C" void kernel_launch(void* const* d_in, const int* in_sizes, int n_in,
                              void* d_out, int out_size, void* d_ws, size_t ws_size,
                              hipStream_t stream) {
  const float* x = (const float*)d_in[0];
  const float* y = (const float*)d_in[1];
  const float* Wq = (const float*)d_in[2];
  const float* Wk = (const float*)d_in[3];
  const float* Wv = (const float*)d_in[4];
  float* out = (float*)d_out;

  char* p = (char*)d_ws;
  u16* xyh = (u16*)p; p += (size_t)16384 * 512 * 2;   // concat f16 (alive thru QK^T)
  u16* Qt  = (u16*)p; p += (size_t)16384 * 512 * 2;   // Q~ = xy*W~ f16
  u16* VTh = (u16*)p; p += (size_t)16384 * 512 * 2;   // V^T f16 [512][16384]
  float* lpart = (float*)p; p += (size_t)16384 * 8 * 4;
  float* linv = (float*)p; p += (size_t)16384 * 4;
  u16* WtT = (u16*)p; p += (size_t)512 * 512 * 2;     // W~^T f16
  u16* Wvh = (u16*)p; p += (size_t)512 * 512 * 2;
  size_t base = (size_t)(p - (char*)d_ws);
  float* wpart = (float*)p;    // 4 MB, dead before S written
  _Float16* Sb = (_Float16*)p; // S/P region

  int nc = (ws_size >= base + (size_t)16384 * 2048 * 2) ? 1 : 2;
  int mrows = 2048 / nc;
  int mt = mrows / 256;

  // converts + W~ precompute
  k_concat_f16<<<8192, 256, 0, stream>>>(x, y, xyh);
  k_wtilde_part<<<256, 256, 0, stream>>>(Wq, Wk, wpart);
  k_wfin<<<68, 256, 0, stream>>>(wpart, Wv, WtT, Wvh);

  // Q~ projection: [16384][512] = xy @ W~T^T  (f16 out)
  k_gemm256<128, 1, 0, 0><<<256, 512, 0, stream>>>(
      xyh, WtT, Qt, 512, 512, 512, 0, 0, 0, 512, 1.0f, 1, 64, 4, nullptr);
  // VT projection: [512][16384] = Wv @ xy^T  (f16 out)
  k_gemm256<128, 1, 0, 0><<<256, 512, 0, stream>>>(
      Wvh, xyh, VTh, 512, 512, 16384, 0, 0, 0, 512, 1.0f, 1, 2, 128, nullptr);

  const float qk_scale = 0.044194173824159216f * 1.4426950408889634f;  // 1/sqrt(512)*log2e
  for (int c = 0; c < nc; ++c) {
    const u16* Qc = Qt + (size_t)c * mrows * 512;
    // P = exp(scale * Q~ xy^T) (f16 out) + row partial sums -> lpart
    k_gemm256<256, 1, 1, 0><<<8 * mt * 8, 512, 0, stream>>>(
        Qc, xyh, Sb, 512, 512, 2048,
        (long long)2048 * 512, (long long)2048 * 512, (long long)mrows * 2048,
        512, qk_scale, 8, mt, 8, lpart + (size_t)c * mrows * 8);
    // linv = 1 / rowsum
    k_inv_l<<<(8 * mrows) / 256, 256, 0, stream>>>(lpart, linv, mrows, c * mrows, 8);
    // O = (P @ VT^T) * linv (f16 in, f32 out)
    k_gemm256<128, 2, 0, 1><<<8 * mt * 4, 512, 0, stream>>>(
        (const u16*)Sb, VTh, out + (size_t)c * mrows * 512, 2048, 16384, 512,
        (long long)mrows * 2048, (long long)2048, (long long)2048 * 512,
        2048, 1.0f, 8, mt, 4, linv + (size_t)c * mrows);
  }
}